// Round 11
// baseline (500.031 us; speedup 1.0000x reference)
//
#include <hip/hip_runtime.h>

// Problem constants (N=8192 tokens, D=256 model dim, dropout p=0.5 -> keep scale 2.0)
#define NT 8192
#define DM 256

typedef float f32x16 __attribute__((ext_vector_type(16)));
typedef float f32x4 __attribute__((ext_vector_type(4)));
typedef __bf16 bf16x8 __attribute__((ext_vector_type(8)));
typedef unsigned int u32x4 __attribute__((ext_vector_type(4)));

#define MFMA32(a, b, c) __builtin_amdgcn_mfma_f32_32x32x16_bf16((a), (b), (c), 0, 0, 0)
#define MFMA16(a, b, c) __builtin_amdgcn_mfma_f32_16x16x32_bf16((a), (b), (c), 0, 0, 0)
#define NEG_INF (-__builtin_inff())

static __device__ __forceinline__ unsigned short f2bf_bits(float f) {
  return __builtin_bit_cast(unsigned short, (__bf16)f);
}
static __device__ __forceinline__ float exp2_fast(float x) {
  return __builtin_amdgcn_exp2f(x);
}
// async global->LDS, 16B per lane. LDS dest is wave-uniform base + lane*16.
static __device__ __forceinline__ void gload_lds16(const void* g, void* l) {
  __builtin_amdgcn_global_load_lds(
      (const __attribute__((address_space(1))) unsigned int*)g,
      (__attribute__((address_space(3))) unsigned int*)l, 16, 0, 0);
}

// ---------------------------------------------------------------------------
// Kernel 0: compress drop_mask (lower triangle, rounded up) into a bitmask,
// bm[i] = 8192 bits (128 u64 words). v9 version (won -43 us): inline mode
// detect; u8 path reads 16 B/lane -> u16/lane packed stores; dword path
// 4 independent ballots/iter.
// ---------------------------------------------------------------------------
__global__ __launch_bounds__(256) void maskpack_kernel(
    const void* __restrict__ mask, unsigned long long* __restrict__ bm) {
  const int t = threadIdx.x, lane = t & 63, w = t >> 6;
  const int r = blockIdx.x + (w << 11);  // grid 2048 -> rows r, r+2048, ...
  const unsigned int* md = (const unsigned int*)mask;
  bool a01 = true, af = true;
#pragma unroll
  for (int k = 0; k < 4; ++k) {
    unsigned int v = md[lane + 64 * k];
    a01 = a01 && (v <= 1u);
    af = af && (v == 0u || v == 0x3F800000u);
  }
  const bool dword_mode = __all(a01) || __all(af);
  unsigned long long* out = bm + (size_t)r * 128;
  if (dword_mode) {
    const unsigned int* mk = (const unsigned int*)mask + (size_t)r * NT;
    const int iters = (r >> 8) + 1;  // 256 cols per iteration
    for (int it = 0; it < iters; ++it) {
      const int j0 = it * 256;
      unsigned int v0 = mk[j0 + lane];
      unsigned int v1 = mk[j0 + 64 + lane];
      unsigned int v2 = mk[j0 + 128 + lane];
      unsigned int v3 = mk[j0 + 192 + lane];
      unsigned long long b0 = __ballot(v0 != 0u);
      unsigned long long b1 = __ballot(v1 != 0u);
      unsigned long long b2 = __ballot(v2 != 0u);
      unsigned long long b3 = __ballot(v3 != 0u);
      if (lane == 0) {
        out[(j0 >> 6) + 0] = b0;
        out[(j0 >> 6) + 1] = b1;
        out[(j0 >> 6) + 2] = b2;
        out[(j0 >> 6) + 3] = b3;
      }
    }
  } else {
    const unsigned char* mk = (const unsigned char*)mask + (size_t)r * NT;
    unsigned short* outs = (unsigned short*)out;
    const int iters = (r >> 10) + 1;  // 1024 cols per wave-iteration
    for (int it = 0; it < iters; ++it) {
      const uint4 d = *(const uint4*)(mk + it * 1024 + lane * 16);
      unsigned int dws[4] = {d.x, d.y, d.z, d.w};
      unsigned int m16 = 0;
#pragma unroll
      for (int k = 0; k < 4; ++k) {
        unsigned int x = dws[k];
        x |= x >> 4;
        x |= x >> 2;
        x |= x >> 1;
        x &= 0x01010101u;
        m16 |= ((x * 0x01020408u) >> 24) << (4 * k);
      }
      outs[it * 64 + lane] = (unsigned short)m16;  // 128 B/wave, coalesced
    }
  }
}

// ---------------------------------------------------------------------------
// Kernel 1: QKV projection. X[8192][256] f32, W[256][256] f32 (torch layout,
// out = X @ W^T). Outputs bf16: Qs (pre-scaled by log2(e)/16), K, and V stored
// transposed Vt[256][8192] PRE-SCALED by 2.0 (dropout keep-scale folded in).
// grid (128 row-blocks, 3 mats), block 256.
// ---------------------------------------------------------------------------
__global__ __launch_bounds__(256) void proj_kernel(
    const float* __restrict__ X, const float* __restrict__ Wq,
    const float* __restrict__ Wk, const float* __restrict__ Wv,
    unsigned short* __restrict__ Qs, unsigned short* __restrict__ Kb,
    unsigned short* __restrict__ Vt) {
  __shared__ __align__(16) unsigned short Xs[64 * 256];
  __shared__ __align__(16) unsigned short Ws[64 * 256];
  __shared__ float Tr[4][32 * 33];
  const int ib = blockIdx.x, mat = blockIdx.y;
  const float* W = (mat == 0) ? Wq : (mat == 1) ? Wk : Wv;
  // mat 0: fold softmax scale (1/sqrt(256)) and log2(e); mat 2: fold dropout 2x
  const float wscale = (mat == 0) ? 0.09016844005556021f : (mat == 2 ? 2.0f : 1.0f);
  const int t = threadIdx.x;
  const int lane = t & 63, w = t >> 6;
  const int m = lane & 31, half = lane >> 5;
  const int i0 = ib * 64;
#pragma unroll
  for (int cc = 0; cc < 8; ++cc) {
    int chunk = t + 256 * cc;
    int rr = chunk >> 5, c = chunk & 31;
    const float4* src = (const float4*)(X + (size_t)(i0 + rr) * 256 + c * 8);
    float4 f0 = src[0], f1 = src[1];
    bf16x8 v;
    v[0] = (__bf16)f0.x; v[1] = (__bf16)f0.y; v[2] = (__bf16)f0.z; v[3] = (__bf16)f0.w;
    v[4] = (__bf16)f1.x; v[5] = (__bf16)f1.y; v[6] = (__bf16)f1.z; v[7] = (__bf16)f1.w;
    *(bf16x8*)&Xs[(rr * 32 + (c ^ (rr & 31))) * 8] = v;
  }
  const int wr = w >> 1, wc = w & 1;
  for (int cb = 0; cb < 4; ++cb) {
    __syncthreads();
#pragma unroll
    for (int cc = 0; cc < 8; ++cc) {
      int chunk = t + 256 * cc;
      int rr = chunk >> 5, c = chunk & 31;
      const float4* src = (const float4*)(W + (size_t)(cb * 64 + rr) * 256 + c * 8);
      float4 f0 = src[0], f1 = src[1];
      bf16x8 v;
      v[0] = (__bf16)(f0.x * wscale); v[1] = (__bf16)(f0.y * wscale);
      v[2] = (__bf16)(f0.z * wscale); v[3] = (__bf16)(f0.w * wscale);
      v[4] = (__bf16)(f1.x * wscale); v[5] = (__bf16)(f1.y * wscale);
      v[6] = (__bf16)(f1.z * wscale); v[7] = (__bf16)(f1.w * wscale);
      *(bf16x8*)&Ws[(rr * 32 + (c ^ (rr & 31))) * 8] = v;
    }
    __syncthreads();
    f32x16 acc = {};
    const int ar = 32 * wr + m;
    const int br = 32 * wc + m;
#pragma unroll
    for (int st = 0; st < 16; ++st) {
      int kc = st * 2 + half;
      bf16x8 a = *(const bf16x8*)&Xs[(ar * 32 + (kc ^ (ar & 31))) * 8];
      bf16x8 b = *(const bf16x8*)&Ws[(br * 32 + (kc ^ (br & 31))) * 8];
      acc = MFMA32(a, b, acc);
    }
    if (mat < 2) {
      unsigned short* O = mat ? Kb : Qs;
#pragma unroll
      for (int r = 0; r < 16; ++r) {
        int row = i0 + 32 * wr + (r & 3) + 8 * (r >> 2) + 4 * half;
        int col = cb * 64 + 32 * wc + m;
        O[(size_t)row * DM + col] = f2bf_bits(acc[r]);
      }
    } else {
      float* T = Tr[w];
#pragma unroll
      for (int r = 0; r < 16; ++r) {
        int rl = (r & 3) + 8 * (r >> 2) + 4 * half;
        T[m * 33 + rl] = acc[r];
      }
      asm volatile("s_waitcnt lgkmcnt(0)" ::: "memory");
#pragma unroll
      for (int q = 0; q < 16; ++q) {
        int dl = 2 * q + half;
        float val = T[dl * 33 + m];
        Vt[(size_t)(cb * 64 + 32 * wc + dl) * NT + i0 + 32 * wr + m] = f2bf_bits(val);
      }
      asm volatile("s_waitcnt lgkmcnt(0)" ::: "memory");
    }
  }
}

// ---------------------------------------------------------------------------
// Kernel 2: flash attention, causal, post-softmax dropout (x2 folded into Vt).
// v11 = v10 math (16-row waves, MFMA16, S^T = K Q^T, O^T = V^T P^T, shuffle-
// butterfly P-frag, no Psh) with a split-resource pipeline:
// - K DOUBLE-buffered (2 x 16 KiB): K(jb+1) prefetched right after barrier 1,
//   in flight for a full compute phase + 2 barriers; drained by a near-free
//   vmcnt(0) at the top of the next iteration. (v10 staged after the second
//   barrier -> full DMA latency exposed every tile.)
// - V SINGLE-buffered (16 KiB): V(jb) staged at barrier 1, consumed only
//   after QK+softmax+butterfly (~350 cyc natural cover); drained by vmcnt(5)
//   (issue order V->K->bits makes the FIFO count exact: leaves K+bits in
//   flight), then barrier 2 -> PV.
// LDS 48 KiB -> 3 blocks/CU = 12 waves/CU. All waitcnt/barriers outside the
// wave-uniform compute guard (each wave drains its own staged chunks before
// the rendezvous -> race-free).
// Lane mapping (16x16x32): m=lane&15, q=lane>>4.
//   A[m][q*8+j], B[q*8+j][m], D[q*4+reg][m].
// ---------------------------------------------------------------------------
__global__ __launch_bounds__(256, 3) void flash_kernel(
    const unsigned short* __restrict__ Qs, const unsigned short* __restrict__ Kg,
    const unsigned short* __restrict__ Vtg, const unsigned int* __restrict__ bm,
    float* __restrict__ ml_out, unsigned short* __restrict__ acc_out) {
  __shared__ __align__(16) unsigned short Ksh[2][32 * 256];  // 2 x 16 KiB
  __shared__ __align__(16) unsigned short Vsh[256 * 32];     // 16 KiB
  const int ib = blockIdx.x;
  const int seg = blockIdx.y;
  const int jb_end = 2 * (ib + 1);   // 32-col tiles
  const int jb0 = seg * 16;
  if (jb0 >= jb_end) return;
  const int jb1 = (jb0 + 16 < jb_end) ? jb0 + 16 : jb_end;
  const int t = threadIdx.x, lane = t & 63, w = t >> 6;
  const int m = lane & 15, q = lane >> 4;
  const int i0 = ib * 64, rw0 = i0 + 16 * w;
  const int myrow = rw0 + m;

  // Q B-fragments, register resident (16 rows x 256 k per wave -> 32 VGPRs)
  bf16x8 qf[8];
  {
    const unsigned short* qp = Qs + (size_t)myrow * DM + q * 8;
#pragma unroll
    for (int st = 0; st < 8; ++st) qf[st] = *(const bf16x8*)(qp + st * 32);
  }
  f32x4 oacc[16] = {};          // O^T: d = ct*16 + q*4 + r, row i = myrow
  float mrun = -1e30f, lrun = 0.f;

#define STAGE_K(JB, B)                                                        \
  {                                                                           \
    const int j32_ = (JB) * 32;                                               \
    _Pragma("unroll") for (int i_ = 0; i_ < 4; ++i_) {                        \
      int chunk = t + 256 * i_;                                               \
      int row = chunk >> 5, slot = chunk & 31;                                \
      gload_lds16(Kg + (size_t)(j32_ + row) * DM + (slot ^ row) * 8,          \
                  &Ksh[B][(size_t)chunk * 8]);                                \
    }                                                                         \
  }
#define STAGE_V(JB)                                                           \
  {                                                                           \
    const int j32_ = (JB) * 32;                                               \
    _Pragma("unroll") for (int i_ = 0; i_ < 4; ++i_) {                        \
      int chunk = t + 256 * i_;                                               \
      int d_ = chunk >> 2, slot = chunk & 3;                                  \
      gload_lds16(Vtg + (size_t)d_ * NT + j32_ + (slot ^ (d_ & 3)) * 8,       \
                  Vsh + (size_t)chunk * 8);                                   \
    }                                                                         \
  }

  STAGE_K(jb0, 0)
  unsigned int bits = bm[(size_t)myrow * 256 + jb0];  // word jb = 32 cols
  for (int jb = jb0; jb < jb1; ++jb) {
    const int buf = (jb - jb0) & 1;
    const int j32 = jb * 32;
    const bool has_next = (jb + 1 < jb1);
    // drain K(jb) (+ prev bits): issued a full iteration ago -> near-free
    asm volatile("s_waitcnt vmcnt(0)" ::: "memory");
    // barrier 1: K(jb) landed everywhere; PV(jb-1) done -> Vsh reusable;
    // QK(jb-1) done -> Ksh[buf^1] reusable.
    __builtin_amdgcn_s_barrier();
    // issue order matters for the vmcnt(5) below: V(4) first, K(4), bits(1).
    STAGE_V(jb)
    unsigned int bits_next = 0;
    if (has_next) {
      STAGE_K(jb + 1, buf ^ 1)
      bits_next = bm[(size_t)myrow * 256 + jb + 1];
    }
    const bool live = (j32 <= rw0 + 15);
    bf16x8 pf;
    if (live) {
      // S^T = K Q^T: 2 j-tiles of 16. Lane holds S[myrow][j32+ct*16+q*4+r].
      const unsigned short* Kb_ = Ksh[buf];
      f32x4 s[2] = {};
#pragma unroll
      for (int st = 0; st < 8; ++st) {
        int kc = st * 4 + q;
#pragma unroll
        for (int ct = 0; ct < 2; ++ct) {
          int jr = ct * 16 + m;
          bf16x8 a = *(const bf16x8*)&Kb_[(jr * 32 + (kc ^ jr)) * 8];
          s[ct] = MFMA16(a, qf[st], s[ct]);
        }
      }
      // causal mask
      if (j32 + 31 > rw0) {
#pragma unroll
        for (int ct = 0; ct < 2; ++ct)
#pragma unroll
          for (int r = 0; r < 4; ++r)
            if (j32 + ct * 16 + q * 4 + r > myrow) s[ct][r] = NEG_INF;
      }
      // online softmax: row = lane (scalar state). Reduce across q-lanes only.
      float mx = fmaxf(fmaxf(fmaxf(s[0][0], s[0][1]), fmaxf(s[0][2], s[0][3])),
                       fmaxf(fmaxf(s[1][0], s[1][1]), fmaxf(s[1][2], s[1][3])));
      mx = fmaxf(mx, __shfl_xor(mx, 16));
      mx = fmaxf(mx, __shfl_xor(mx, 32));
      const float mn = fmaxf(mrun, mx);
#pragma unroll
      for (int ct = 0; ct < 2; ++ct)
#pragma unroll
        for (int r = 0; r < 4; ++r) s[ct][r] = exp2_fast(s[ct][r] - mn);
      float rs = (s[0][0] + s[0][1]) + (s[0][2] + s[0][3]) +
                 (s[1][0] + s[1][1]) + (s[1][2] + s[1][3]);
      rs += __shfl_xor(rs, 16);
      rs += __shfl_xor(rs, 32);
      if (__all(mn == mrun)) {
        lrun += rs;                  // running max unchanged: skip O rescale
      } else {
        float alpha = exp2_fast(mrun - mn);
        lrun = lrun * alpha + rs;
#pragma unroll
        for (int ct = 0; ct < 16; ++ct)
#pragma unroll
          for (int r = 0; r < 4; ++r) oacc[ct][r] *= alpha;
        mrun = mn;
      }
      // dropout (zero-only; 2x lives in Vt) + pack to bf16 dword quads.
      unsigned int A0, A1, B0, B1;
      {
        unsigned int bbA = bits >> (q * 4);
        unsigned int bbB = bits >> (16 + q * 4);
        float a0 = (bbA & 1u) ? s[0][0] : 0.f, a1 = (bbA & 2u) ? s[0][1] : 0.f;
        float a2 = (bbA & 4u) ? s[0][2] : 0.f, a3 = (bbA & 8u) ? s[0][3] : 0.f;
        float b0 = (bbB & 1u) ? s[1][0] : 0.f, b1 = (bbB & 2u) ? s[1][1] : 0.f;
        float b2 = (bbB & 4u) ? s[1][2] : 0.f, b3 = (bbB & 8u) ? s[1][3] : 0.f;
        A0 = (unsigned)f2bf_bits(a0) | ((unsigned)f2bf_bits(a1) << 16);
        A1 = (unsigned)f2bf_bits(a2) | ((unsigned)f2bf_bits(a3) << 16);
        B0 = (unsigned)f2bf_bits(b0) | ((unsigned)f2bf_bits(b1) << 16);
        B1 = (unsigned)f2bf_bits(b2) | ((unsigned)f2bf_bits(b3) << 16);
      }
      // 2-stage butterfly among q-lanes of this m-group: lane (m,q) ends
      // with P^T B-frag = S[myrow][j32+8q .. 8q+7] (verified in v10).
      unsigned int own0 = (q & 2) ? B0 : A0, own1 = (q & 2) ? B1 : A1;
      unsigned int sA0 = (q & 2) ? A0 : B0, sA1 = (q & 2) ? A1 : B1;
      unsigned int r10 = __shfl_xor(sA0, 32);
      unsigned int r11 = __shfl_xor(sA1, 32);
      const bool selOwn = ((q ^ (q >> 1)) & 1) != 0;
      unsigned int s20 = selOwn ? own0 : r10;
      unsigned int s21 = selOwn ? own1 : r11;
      unsigned int r20 = __shfl_xor(s20, 16);
      unsigned int r21 = __shfl_xor(s21, 16);
      unsigned int lo0 = (q == 0) ? own0 : (q == 2) ? r10 : r20;
      unsigned int lo1 = (q == 0) ? own1 : (q == 2) ? r11 : r21;
      unsigned int hi0 = (q == 3) ? own0 : (q == 1) ? r10 : r20;
      unsigned int hi1 = (q == 3) ? own1 : (q == 1) ? r11 : r21;
      pf = __builtin_bit_cast(bf16x8, (u32x4){lo0, lo1, hi0, hi1});
    }
    // drain V(jb): vmcnt(5) leaves K(jb+1)+bits_next (5 newest) in flight.
    if (has_next) {
      asm volatile("s_waitcnt vmcnt(5)" ::: "memory");
    } else {
      asm volatile("s_waitcnt vmcnt(0)" ::: "memory");
    }
    // barrier 2: all waves' V(jb) chunks landed -> Vsh complete.
    __builtin_amdgcn_s_barrier();
    if (live) {
      // O^T += V^T P^T: A = Vt rows (d = ct*16+m), k = 32 j's (one MFMA/ct)
#pragma unroll
      for (int ct = 0; ct < 16; ++ct) {
        int d = ct * 16 + m;
        bf16x8 a = *(const bf16x8*)&Vsh[(d * 4 + (q ^ (d & 3))) * 8];
        oacc[ct] = MFMA16(a, pf, oacc[ct]);
      }
    }
    bits = bits_next;
  }
#undef STAGE_K
#undef STAGE_V
  // write segment partials. g = segment slot for (ib, seg).
  const int a_ = ib >> 3, r_ = ib & 7;
  const int g = 4 * a_ * (a_ + 1) + r_ * (a_ + 1) + seg;
  if (q == 0) {
    float* mlb = ml_out + ((size_t)g * 64 + 16 * w + m) * 2;
    mlb[0] = mrun;
    mlb[1] = lrun;
  }
  unsigned short* ab = acc_out + ((size_t)g * 64 + 16 * w + m) * DM;
#pragma unroll
  for (int ct = 0; ct < 16; ++ct) {
    unsigned long long pk = 0;
#pragma unroll
    for (int r = 0; r < 4; ++r)
      pk |= (unsigned long long)f2bf_bits(oacc[ct][r]) << (16 * r);
    *(unsigned long long*)&ab[ct * 16 + q * 4] = pk;  // 8B contiguous quads
  }
}

// ---------------------------------------------------------------------------
// Kernel 3: combine segment partials. O = sum_s w_s*acc_s / sum_s w_s*l_s,
// w_s = 2^(m_s - M). grid 256 blocks x 256 thr; thread = (row, 32-col group).
// Row blocks are 64 rows; slots g0(ib) = 4a(a+1)+r(a+1), ns = a+1 (ib=8a+r).
// ---------------------------------------------------------------------------
__global__ __launch_bounds__(256) void combine_kernel(
    const float* __restrict__ ml, const unsigned short* __restrict__ pacc,
    float* __restrict__ out) {
  const int t = threadIdx.x;
  const int row = blockIdx.x * 32 + (t >> 3);
  const int cg = (t & 7) * 32;
  const int ib = row >> 6, rib = row & 63;
  const int a = ib >> 3, r = ib & 7;
  const int g0 = 4 * a * (a + 1) + r * (a + 1);
  const int ns = a + 1;
  float M = -1e30f;
  for (int s = 0; s < ns; ++s) M = fmaxf(M, ml[((size_t)(g0 + s) * 64 + rib) * 2]);
  float Wd = 0.f;
  float acc[32];
#pragma unroll
  for (int j = 0; j < 32; ++j) acc[j] = 0.f;
  for (int s = 0; s < ns; ++s) {
    const float* mls = ml + ((size_t)(g0 + s) * 64 + rib) * 2;
    float wv = exp2_fast(mls[0] - M);
    Wd += wv * mls[1];
    const unsigned short* pa = pacc + ((size_t)(g0 + s) * 64 + rib) * DM + cg;
#pragma unroll
    for (int v4 = 0; v4 < 4; ++v4) {
      bf16x8 b = *(const bf16x8*)(pa + v4 * 8);
#pragma unroll
      for (int j = 0; j < 8; ++j) acc[v4 * 8 + j] += wv * (float)b[j];
    }
  }
  float inv = 1.0f / Wd;
#pragma unroll
  for (int j = 0; j < 32; ++j) out[(size_t)row * DM + cg + j] = acc[j] * inv;
}

// ---------------------------------------------------------------------------
extern "C" void kernel_launch(void* const* d_in, const int* in_sizes, int n_in,
                              void* d_out, int out_size, void* d_ws, size_t ws_size,
                              hipStream_t stream) {
  const float* X  = (const float*)d_in[0];
  const float* Wq = (const float*)d_in[1];
  const float* Wk = (const float*)d_in[2];
  const float* Wv = (const float*)d_in[3];
  const void* mask = d_in[4];
  float* out = (float*)d_out;

  char* ws = (char*)d_ws;
  unsigned short* Qs = (unsigned short*)(ws + 4096);
  unsigned short* Kb = Qs + (size_t)NT * DM;
  unsigned short* Vt = Kb + (size_t)NT * DM;
  float* ml = (float*)(Vt + (size_t)NT * DM);                 // 1088*64*2 f32
  unsigned short* pacc = (unsigned short*)(ml + (size_t)1088 * 64 * 2);
  unsigned long long* bmw = (unsigned long long*)((char*)pacc + (size_t)1088 * 64 * DM * 2);
  // total ws use: 4096 + 12 MiB + 544 KiB + 34 MiB + 8 MiB ~= 55 MiB

  maskpack_kernel<<<2048, 256, 0, stream>>>(mask, bmw);
  proj_kernel<<<dim3(128, 3), 256, 0, stream>>>(X, Wq, Wk, Wv, Qs, Kb, Vt);
  flash_kernel<<<dim3(128, 16), 256, 0, stream>>>(Qs, Kb, Vt, (const unsigned int*)bmw,
                                                  ml, pacc);
  combine_kernel<<<256, 256, 0, stream>>>(ml, pacc, out);
}

// Round 12
// 466.822 us; speedup vs baseline: 1.0711x; 1.0711x over previous
//
#include <hip/hip_runtime.h>

// Problem constants (N=8192 tokens, D=256 model dim, dropout p=0.5 -> keep scale 2.0)
#define NT 8192
#define DM 256

typedef float f32x16 __attribute__((ext_vector_type(16)));
typedef float f32x4 __attribute__((ext_vector_type(4)));
typedef __bf16 bf16x8 __attribute__((ext_vector_type(8)));
typedef unsigned int u32x4 __attribute__((ext_vector_type(4)));

#define MFMA32(a, b, c) __builtin_amdgcn_mfma_f32_32x32x16_bf16((a), (b), (c), 0, 0, 0)
#define MFMA16(a, b, c) __builtin_amdgcn_mfma_f32_16x16x32_bf16((a), (b), (c), 0, 0, 0)
#define NEG_INF (-__builtin_inff())

static __device__ __forceinline__ unsigned short f2bf_bits(float f) {
  return __builtin_bit_cast(unsigned short, (__bf16)f);
}
static __device__ __forceinline__ float exp2_fast(float x) {
  return __builtin_amdgcn_exp2f(x);
}
// async global->LDS, 16B per lane. LDS dest is wave-uniform base + lane*16.
static __device__ __forceinline__ void gload_lds16(const void* g, void* l) {
  __builtin_amdgcn_global_load_lds(
      (const __attribute__((address_space(1))) unsigned int*)g,
      (__attribute__((address_space(3))) unsigned int*)l, 16, 0, 0);
}

// ---------------------------------------------------------------------------
// Kernel 0: compress drop_mask (lower triangle, rounded up) into a bitmask,
// bm[i] = 8192 bits (128 u64 words). v9 version (won -43 us): inline mode
// detect; u8 path reads 16 B/lane -> u16/lane packed stores; dword path
// 4 independent ballots/iter.
// ---------------------------------------------------------------------------
__global__ __launch_bounds__(256) void maskpack_kernel(
    const void* __restrict__ mask, unsigned long long* __restrict__ bm) {
  const int t = threadIdx.x, lane = t & 63, w = t >> 6;
  const int r = blockIdx.x + (w << 11);  // grid 2048 -> rows r, r+2048, ...
  const unsigned int* md = (const unsigned int*)mask;
  bool a01 = true, af = true;
#pragma unroll
  for (int k = 0; k < 4; ++k) {
    unsigned int v = md[lane + 64 * k];
    a01 = a01 && (v <= 1u);
    af = af && (v == 0u || v == 0x3F800000u);
  }
  const bool dword_mode = __all(a01) || __all(af);
  unsigned long long* out = bm + (size_t)r * 128;
  if (dword_mode) {
    const unsigned int* mk = (const unsigned int*)mask + (size_t)r * NT;
    const int iters = (r >> 8) + 1;  // 256 cols per iteration
    for (int it = 0; it < iters; ++it) {
      const int j0 = it * 256;
      unsigned int v0 = mk[j0 + lane];
      unsigned int v1 = mk[j0 + 64 + lane];
      unsigned int v2 = mk[j0 + 128 + lane];
      unsigned int v3 = mk[j0 + 192 + lane];
      unsigned long long b0 = __ballot(v0 != 0u);
      unsigned long long b1 = __ballot(v1 != 0u);
      unsigned long long b2 = __ballot(v2 != 0u);
      unsigned long long b3 = __ballot(v3 != 0u);
      if (lane == 0) {
        out[(j0 >> 6) + 0] = b0;
        out[(j0 >> 6) + 1] = b1;
        out[(j0 >> 6) + 2] = b2;
        out[(j0 >> 6) + 3] = b3;
      }
    }
  } else {
    const unsigned char* mk = (const unsigned char*)mask + (size_t)r * NT;
    unsigned short* outs = (unsigned short*)out;
    const int iters = (r >> 10) + 1;  // 1024 cols per wave-iteration
    for (int it = 0; it < iters; ++it) {
      const uint4 d = *(const uint4*)(mk + it * 1024 + lane * 16);
      unsigned int dws[4] = {d.x, d.y, d.z, d.w};
      unsigned int m16 = 0;
#pragma unroll
      for (int k = 0; k < 4; ++k) {
        unsigned int x = dws[k];
        x |= x >> 4;
        x |= x >> 2;
        x |= x >> 1;
        x &= 0x01010101u;
        m16 |= ((x * 0x01020408u) >> 24) << (4 * k);
      }
      outs[it * 64 + lane] = (unsigned short)m16;  // 128 B/wave, coalesced
    }
  }
}

// ---------------------------------------------------------------------------
// Kernel 1: QKV projection. X[8192][256] f32, W[256][256] f32 (torch layout,
// out = X @ W^T). Outputs bf16: Qs (pre-scaled by log2(e)/16), K, and V stored
// transposed Vt[256][8192] PRE-SCALED by 2.0 (dropout keep-scale folded in).
// grid (128 row-blocks, 3 mats), block 256.
// ---------------------------------------------------------------------------
__global__ __launch_bounds__(256) void proj_kernel(
    const float* __restrict__ X, const float* __restrict__ Wq,
    const float* __restrict__ Wk, const float* __restrict__ Wv,
    unsigned short* __restrict__ Qs, unsigned short* __restrict__ Kb,
    unsigned short* __restrict__ Vt) {
  __shared__ __align__(16) unsigned short Xs[64 * 256];
  __shared__ __align__(16) unsigned short Ws[64 * 256];
  __shared__ float Tr[4][32 * 33];
  const int ib = blockIdx.x, mat = blockIdx.y;
  const float* W = (mat == 0) ? Wq : (mat == 1) ? Wk : Wv;
  // mat 0: fold softmax scale (1/sqrt(256)) and log2(e); mat 2: fold dropout 2x
  const float wscale = (mat == 0) ? 0.09016844005556021f : (mat == 2 ? 2.0f : 1.0f);
  const int t = threadIdx.x;
  const int lane = t & 63, w = t >> 6;
  const int m = lane & 31, half = lane >> 5;
  const int i0 = ib * 64;
#pragma unroll
  for (int cc = 0; cc < 8; ++cc) {
    int chunk = t + 256 * cc;
    int rr = chunk >> 5, c = chunk & 31;
    const float4* src = (const float4*)(X + (size_t)(i0 + rr) * 256 + c * 8);
    float4 f0 = src[0], f1 = src[1];
    bf16x8 v;
    v[0] = (__bf16)f0.x; v[1] = (__bf16)f0.y; v[2] = (__bf16)f0.z; v[3] = (__bf16)f0.w;
    v[4] = (__bf16)f1.x; v[5] = (__bf16)f1.y; v[6] = (__bf16)f1.z; v[7] = (__bf16)f1.w;
    *(bf16x8*)&Xs[(rr * 32 + (c ^ (rr & 31))) * 8] = v;
  }
  const int wr = w >> 1, wc = w & 1;
  for (int cb = 0; cb < 4; ++cb) {
    __syncthreads();
#pragma unroll
    for (int cc = 0; cc < 8; ++cc) {
      int chunk = t + 256 * cc;
      int rr = chunk >> 5, c = chunk & 31;
      const float4* src = (const float4*)(W + (size_t)(cb * 64 + rr) * 256 + c * 8);
      float4 f0 = src[0], f1 = src[1];
      bf16x8 v;
      v[0] = (__bf16)(f0.x * wscale); v[1] = (__bf16)(f0.y * wscale);
      v[2] = (__bf16)(f0.z * wscale); v[3] = (__bf16)(f0.w * wscale);
      v[4] = (__bf16)(f1.x * wscale); v[5] = (__bf16)(f1.y * wscale);
      v[6] = (__bf16)(f1.z * wscale); v[7] = (__bf16)(f1.w * wscale);
      *(bf16x8*)&Ws[(rr * 32 + (c ^ (rr & 31))) * 8] = v;
    }
    __syncthreads();
    f32x16 acc = {};
    const int ar = 32 * wr + m;
    const int br = 32 * wc + m;
#pragma unroll
    for (int st = 0; st < 16; ++st) {
      int kc = st * 2 + half;
      bf16x8 a = *(const bf16x8*)&Xs[(ar * 32 + (kc ^ (ar & 31))) * 8];
      bf16x8 b = *(const bf16x8*)&Ws[(br * 32 + (kc ^ (br & 31))) * 8];
      acc = MFMA32(a, b, acc);
    }
    if (mat < 2) {
      unsigned short* O = mat ? Kb : Qs;
#pragma unroll
      for (int r = 0; r < 16; ++r) {
        int row = i0 + 32 * wr + (r & 3) + 8 * (r >> 2) + 4 * half;
        int col = cb * 64 + 32 * wc + m;
        O[(size_t)row * DM + col] = f2bf_bits(acc[r]);
      }
    } else {
      float* T = Tr[w];
#pragma unroll
      for (int r = 0; r < 16; ++r) {
        int rl = (r & 3) + 8 * (r >> 2) + 4 * half;
        T[m * 33 + rl] = acc[r];
      }
      asm volatile("s_waitcnt lgkmcnt(0)" ::: "memory");
#pragma unroll
      for (int q = 0; q < 16; ++q) {
        int dl = 2 * q + half;
        float val = T[dl * 33 + m];
        Vt[(size_t)(cb * 64 + 32 * wc + dl) * NT + i0 + 32 * wr + m] = f2bf_bits(val);
      }
      asm volatile("s_waitcnt lgkmcnt(0)" ::: "memory");
    }
  }
}

// ---------------------------------------------------------------------------
// Kernel 2: flash attention, causal, post-softmax dropout (x2 folded into Vt).
// v10 (best known, 467.1 us) restored verbatim after v11's split-resource
// pipeline regressed (+33 us: mid-tile vmcnt(5) drain not covered by the
// ~350-cyc QK window). v10 = 16-row waves, MFMA16, S^T = K Q^T,
// O^T = V^T P^T, P-frag built by a 2-stage 4-lane shuffle butterfly (no Psh,
// no lgkm drain), single-buffered 32 KiB LDS -> 3 blocks/CU = 12 waves/CU.
// Pipeline: STAGE(jb+1) issued after the post-compute __syncthreads; exposed
// DMA latency covered by the 3 resident blocks (4 structural alternatives
// tried across v4/v7/v8/v11 -- none beat this).
// Lane mapping (16x16x32): m=lane&15, q=lane>>4.
//   A[m][q*8+j], B[q*8+j][m], D[q*4+reg][m].
// ---------------------------------------------------------------------------
__global__ __launch_bounds__(256, 3) void flash_kernel(
    const unsigned short* __restrict__ Qs, const unsigned short* __restrict__ Kg,
    const unsigned short* __restrict__ Vtg, const unsigned int* __restrict__ bm,
    float* __restrict__ ml_out, unsigned short* __restrict__ acc_out) {
  __shared__ __align__(16) unsigned short Ksh[32 * 256];   // 16 KiB
  __shared__ __align__(16) unsigned short Vsh[256 * 32];   // 16 KiB
  const int ib = blockIdx.x;
  const int seg = blockIdx.y;
  const int jb_end = 2 * (ib + 1);   // 32-col tiles
  const int jb0 = seg * 16;
  if (jb0 >= jb_end) return;
  const int jb1 = (jb0 + 16 < jb_end) ? jb0 + 16 : jb_end;
  const int t = threadIdx.x, lane = t & 63, w = t >> 6;
  const int m = lane & 15, q = lane >> 4;
  const int i0 = ib * 64, rw0 = i0 + 16 * w;
  const int myrow = rw0 + m;

  // Q B-fragments, register resident (16 rows x 256 k per wave -> 32 VGPRs)
  bf16x8 qf[8];
  {
    const unsigned short* qp = Qs + (size_t)myrow * DM + q * 8;
#pragma unroll
    for (int st = 0; st < 8; ++st) qf[st] = *(const bf16x8*)(qp + st * 32);
  }
  f32x4 oacc[16] = {};          // O^T: d = ct*16 + q*4 + r, row i = myrow
  float mrun = -1e30f, lrun = 0.f;

#define STAGE(JB)                                                             \
  {                                                                           \
    const int j32_ = (JB) * 32;                                               \
    _Pragma("unroll") for (int i_ = 0; i_ < 4; ++i_) {                        \
      int chunk = t + 256 * i_;                                               \
      int row = chunk >> 5, slot = chunk & 31;                                \
      gload_lds16(Kg + (size_t)(j32_ + row) * DM + (slot ^ row) * 8,          \
                  Ksh + (size_t)chunk * 8);                                   \
    }                                                                         \
    _Pragma("unroll") for (int i_ = 0; i_ < 4; ++i_) {                        \
      int chunk = t + 256 * i_;                                               \
      int d_ = chunk >> 2, slot = chunk & 3;                                  \
      gload_lds16(Vtg + (size_t)d_ * NT + j32_ + (slot ^ (d_ & 3)) * 8,       \
                  Vsh + (size_t)chunk * 8);                                   \
    }                                                                         \
  }

  STAGE(jb0)
  unsigned int bits = bm[(size_t)myrow * 256 + jb0];  // word jb = 32 cols
  for (int jb = jb0; jb < jb1; ++jb) {
    const int j32 = jb * 32;
    __syncthreads();  // drains tile-jb DMA (vmcnt 0) + all waves arrived
    if (j32 <= rw0 + 15) {  // wave has at least one unmasked (row, col) pair
      // S^T = K Q^T: 2 j-tiles of 16. Lane holds S[myrow][j32+ct*16+q*4+r].
      f32x4 s[2] = {};
#pragma unroll
      for (int st = 0; st < 8; ++st) {
        int kc = st * 4 + q;
#pragma unroll
        for (int ct = 0; ct < 2; ++ct) {
          int jr = ct * 16 + m;
          bf16x8 a = *(const bf16x8*)&Ksh[(jr * 32 + (kc ^ jr)) * 8];
          s[ct] = MFMA16(a, qf[st], s[ct]);
        }
      }
      // causal mask
      if (j32 + 31 > rw0) {
#pragma unroll
        for (int ct = 0; ct < 2; ++ct)
#pragma unroll
          for (int r = 0; r < 4; ++r)
            if (j32 + ct * 16 + q * 4 + r > myrow) s[ct][r] = NEG_INF;
      }
      // online softmax: row = lane (scalar state). Reduce across q-lanes only.
      float mx = fmaxf(fmaxf(fmaxf(s[0][0], s[0][1]), fmaxf(s[0][2], s[0][3])),
                       fmaxf(fmaxf(s[1][0], s[1][1]), fmaxf(s[1][2], s[1][3])));
      mx = fmaxf(mx, __shfl_xor(mx, 16));
      mx = fmaxf(mx, __shfl_xor(mx, 32));
      const float mn = fmaxf(mrun, mx);
#pragma unroll
      for (int ct = 0; ct < 2; ++ct)
#pragma unroll
        for (int r = 0; r < 4; ++r) s[ct][r] = exp2_fast(s[ct][r] - mn);
      float rs = (s[0][0] + s[0][1]) + (s[0][2] + s[0][3]) +
                 (s[1][0] + s[1][1]) + (s[1][2] + s[1][3]);
      rs += __shfl_xor(rs, 16);
      rs += __shfl_xor(rs, 32);
      if (__all(mn == mrun)) {
        lrun += rs;                  // running max unchanged: skip O rescale
      } else {
        float alpha = exp2_fast(mrun - mn);
        lrun = lrun * alpha + rs;
#pragma unroll
        for (int ct = 0; ct < 16; ++ct)
#pragma unroll
          for (int r = 0; r < 4; ++r) oacc[ct][r] *= alpha;
        mrun = mn;
      }
      // dropout (zero-only; 2x lives in Vt) + pack to bf16 dword quads.
      // Quad A = ct0 (j-local q*4+r), quad B = ct1 (16 + q*4+r), 2 dwords each.
      unsigned int A0, A1, B0, B1;
      {
        unsigned int bbA = bits >> (q * 4);
        unsigned int bbB = bits >> (16 + q * 4);
        float a0 = (bbA & 1u) ? s[0][0] : 0.f, a1 = (bbA & 2u) ? s[0][1] : 0.f;
        float a2 = (bbA & 4u) ? s[0][2] : 0.f, a3 = (bbA & 8u) ? s[0][3] : 0.f;
        float b0 = (bbB & 1u) ? s[1][0] : 0.f, b1 = (bbB & 2u) ? s[1][1] : 0.f;
        float b2 = (bbB & 4u) ? s[1][2] : 0.f, b3 = (bbB & 8u) ? s[1][3] : 0.f;
        A0 = (unsigned)f2bf_bits(a0) | ((unsigned)f2bf_bits(a1) << 16);
        A1 = (unsigned)f2bf_bits(a2) | ((unsigned)f2bf_bits(a3) << 16);
        B0 = (unsigned)f2bf_bits(b0) | ((unsigned)f2bf_bits(b1) << 16);
        B1 = (unsigned)f2bf_bits(b2) | ((unsigned)f2bf_bits(b3) << 16);
      }
      // 2-stage butterfly among q-lanes of this m-group to build the P^T
      // B-frag: lane (m,q) ends with S[myrow][j32+8q .. 8q+7].
      // Stage 1 (xor 32): send partner's wanted type; keep own wanted type.
      unsigned int own0 = (q & 2) ? B0 : A0, own1 = (q & 2) ? B1 : A1;
      unsigned int sA0 = (q & 2) ? A0 : B0, sA1 = (q & 2) ? A1 : B1;
      unsigned int r10 = __shfl_xor(sA0, 32);
      unsigned int r11 = __shfl_xor(sA1, 32);
      // Stage 2 (xor 16): sel = (q ^ (q>>1)) & 1 chooses own vs stage-1 recv.
      const bool selOwn = ((q ^ (q >> 1)) & 1) != 0;
      unsigned int s20 = selOwn ? own0 : r10;
      unsigned int s21 = selOwn ? own1 : r11;
      unsigned int r20 = __shfl_xor(s20, 16);
      unsigned int r21 = __shfl_xor(s21, 16);
      // Final (lo = j 8q..8q+3, hi = 8q+4..8q+7):
      //  q0: lo=own hi=r2 | q1: lo=r2 hi=r1 | q2: lo=r1 hi=r2 | q3: lo=r2 hi=own
      unsigned int lo0 = (q == 0) ? A0 : (q == 2) ? r10 : r20;
      unsigned int lo1 = (q == 0) ? A1 : (q == 2) ? r11 : r21;
      unsigned int hi0 = (q == 3) ? B0 : (q == 1) ? r10 : r20;
      unsigned int hi1 = (q == 3) ? B1 : (q == 1) ? r11 : r21;
      bf16x8 pf = __builtin_bit_cast(bf16x8, (u32x4){lo0, lo1, hi0, hi1});
      // O^T += V^T P^T: A = Vt rows (d = ct*16+m), k = 32 j's (one MFMA/ct)
#pragma unroll
      for (int ct = 0; ct < 16; ++ct) {
        int d = ct * 16 + m;
        bf16x8 a = *(const bf16x8*)&Vsh[(d * 4 + (q ^ (d & 3))) * 8];
        oacc[ct] = MFMA16(a, pf, oacc[ct]);
      }
    }
    __syncthreads();  // all waves done reading K/V(jb)
    if (jb + 1 < jb1) {
      STAGE(jb + 1)
      bits = bm[(size_t)myrow * 256 + jb + 1];
    }
  }
#undef STAGE
  // write segment partials. g = segment slot for (ib, seg).
  const int a_ = ib >> 3, r_ = ib & 7;
  const int g = 4 * a_ * (a_ + 1) + r_ * (a_ + 1) + seg;
  if (q == 0) {
    float* mlb = ml_out + ((size_t)g * 64 + 16 * w + m) * 2;
    mlb[0] = mrun;
    mlb[1] = lrun;
  }
  unsigned short* ab = acc_out + ((size_t)g * 64 + 16 * w + m) * DM;
#pragma unroll
  for (int ct = 0; ct < 16; ++ct) {
    unsigned long long pk = 0;
#pragma unroll
    for (int r = 0; r < 4; ++r)
      pk |= (unsigned long long)f2bf_bits(oacc[ct][r]) << (16 * r);
    *(unsigned long long*)&ab[ct * 16 + q * 4] = pk;  // 8B contiguous quads
  }
}

// ---------------------------------------------------------------------------
// Kernel 3: combine segment partials. O = sum_s w_s*acc_s / sum_s w_s*l_s,
// w_s = 2^(m_s - M). grid 256 blocks x 256 thr; thread = (row, 32-col group).
// Row blocks are 64 rows; slots g0(ib) = 4a(a+1)+r(a+1), ns = a+1 (ib=8a+r).
// ---------------------------------------------------------------------------
__global__ __launch_bounds__(256) void combine_kernel(
    const float* __restrict__ ml, const unsigned short* __restrict__ pacc,
    float* __restrict__ out) {
  const int t = threadIdx.x;
  const int row = blockIdx.x * 32 + (t >> 3);
  const int cg = (t & 7) * 32;
  const int ib = row >> 6, rib = row & 63;
  const int a = ib >> 3, r = ib & 7;
  const int g0 = 4 * a * (a + 1) + r * (a + 1);
  const int ns = a + 1;
  float M = -1e30f;
  for (int s = 0; s < ns; ++s) M = fmaxf(M, ml[((size_t)(g0 + s) * 64 + rib) * 2]);
  float Wd = 0.f;
  float acc[32];
#pragma unroll
  for (int j = 0; j < 32; ++j) acc[j] = 0.f;
  for (int s = 0; s < ns; ++s) {
    const float* mls = ml + ((size_t)(g0 + s) * 64 + rib) * 2;
    float wv = exp2_fast(mls[0] - M);
    Wd += wv * mls[1];
    const unsigned short* pa = pacc + ((size_t)(g0 + s) * 64 + rib) * DM + cg;
#pragma unroll
    for (int v4 = 0; v4 < 4; ++v4) {
      bf16x8 b = *(const bf16x8*)(pa + v4 * 8);
#pragma unroll
      for (int j = 0; j < 8; ++j) acc[v4 * 8 + j] += wv * (float)b[j];
    }
  }
  float inv = 1.0f / Wd;
#pragma unroll
  for (int j = 0; j < 32; ++j) out[(size_t)row * DM + cg + j] = acc[j] * inv;
}

// ---------------------------------------------------------------------------
extern "C" void kernel_launch(void* const* d_in, const int* in_sizes, int n_in,
                              void* d_out, int out_size, void* d_ws, size_t ws_size,
                              hipStream_t stream) {
  const float* X  = (const float*)d_in[0];
  const float* Wq = (const float*)d_in[1];
  const float* Wk = (const float*)d_in[2];
  const float* Wv = (const float*)d_in[3];
  const void* mask = d_in[4];
  float* out = (float*)d_out;

  char* ws = (char*)d_ws;
  unsigned short* Qs = (unsigned short*)(ws + 4096);
  unsigned short* Kb = Qs + (size_t)NT * DM;
  unsigned short* Vt = Kb + (size_t)NT * DM;
  float* ml = (float*)(Vt + (size_t)NT * DM);                 // 1088*64*2 f32
  unsigned short* pacc = (unsigned short*)(ml + (size_t)1088 * 64 * 2);
  unsigned long long* bmw = (unsigned long long*)((char*)pacc + (size_t)1088 * 64 * DM * 2);
  // total ws use: 4096 + 12 MiB + 544 KiB + 34 MiB + 8 MiB ~= 55 MiB

  maskpack_kernel<<<2048, 256, 0, stream>>>(mask, bmw);
  proj_kernel<<<dim3(128, 3), 256, 0, stream>>>(X, Wq, Wk, Wv, Qs, Kb, Vt);
  flash_kernel<<<dim3(128, 16), 256, 0, stream>>>(Qs, Kb, Vt, (const unsigned int*)bmw,
                                                  ml, pacc);
  combine_kernel<<<256, 256, 0, stream>>>(ml, pacc, out);
}